// Round 1
// baseline (703.090 us; speedup 1.0000x reference)
//
#include <hip/hip_runtime.h>
#include <hip/hip_bf16.h>

// S=2048, E=2048, H=16, D=128
#define S_LEN 2048
#define EMB   2048
#define NH    16
#define HD    128

typedef __bf16 bf16x8 __attribute__((ext_vector_type(8)));
typedef __bf16 bf16x4 __attribute__((ext_vector_type(4)));
typedef float  f32x4  __attribute__((ext_vector_type(4)));

__device__ __forceinline__ void async_copy16(void* lds, const void* g) {
  __builtin_amdgcn_global_load_lds((__attribute__((address_space(1))) void*)(void*)g,
                                   (__attribute__((address_space(3))) void*)lds, 16, 0, 0);
}

__device__ __forceinline__ float gelu_tanh(float x) {
  float x3 = x * x * x;
  float t  = 0.7978845608028654f * (x + 0.044715f * x3);
  // tanh(t) = 1 - 2/(e^{2t}+1)
  float th = 1.0f - 2.0f / (__expf(2.0f * t) + 1.0f);
  return 0.5f * x * (1.0f + th);
}

// ---------------- fp32 -> bf16 cast (weights) ----------------
__global__ __launch_bounds__(256) void cast_kernel(const float* __restrict__ in,
                                                   __bf16* __restrict__ out, int n) {
  int i = (blockIdx.x * 256 + threadIdx.x) * 4;
  if (i >= n) return;
  float4 v = *(const float4*)(in + i);
  bf16x4 o;
  o[0] = (__bf16)v.x; o[1] = (__bf16)v.y; o[2] = (__bf16)v.z; o[3] = (__bf16)v.w;
  *(bf16x4*)(out + i) = o;
}

// ---------------- LayerNorm (no bias): out_bf16 = (x-mu)*rsqrt(var+eps)*w ----------------
__global__ __launch_bounds__(256) void ln_kernel(const float* __restrict__ x,
                                                 const float* __restrict__ w,
                                                 __bf16* __restrict__ out) {
  int row = blockIdx.x;
  int t = threadIdx.x;
  const float* xr = x + (size_t)row * EMB;
  float4 a = *(const float4*)(xr + t * 8);
  float4 b = *(const float4*)(xr + t * 8 + 4);
  float s  = a.x + a.y + a.z + a.w + b.x + b.y + b.z + b.w;
  float sq = a.x*a.x + a.y*a.y + a.z*a.z + a.w*a.w + b.x*b.x + b.y*b.y + b.z*b.z + b.w*b.w;
  #pragma unroll
  for (int o = 32; o > 0; o >>= 1) { s += __shfl_xor(s, o); sq += __shfl_xor(sq, o); }
  __shared__ float red[8];
  if ((t & 63) == 0) { red[t >> 6] = s; red[(t >> 6) + 4] = sq; }
  __syncthreads();
  s  = red[0] + red[1] + red[2] + red[3];
  sq = red[4] + red[5] + red[6] + red[7];
  float mu  = s * (1.0f / EMB);
  float var = sq * (1.0f / EMB) - mu * mu;
  float rs  = rsqrtf(var + 1e-5f);
  float4 w1 = *(const float4*)(w + t * 8);
  float4 w2 = *(const float4*)(w + t * 8 + 4);
  bf16x8 ov;
  ov[0] = (__bf16)((a.x - mu) * rs * w1.x);
  ov[1] = (__bf16)((a.y - mu) * rs * w1.y);
  ov[2] = (__bf16)((a.z - mu) * rs * w1.z);
  ov[3] = (__bf16)((a.w - mu) * rs * w1.w);
  ov[4] = (__bf16)((b.x - mu) * rs * w2.x);
  ov[5] = (__bf16)((b.y - mu) * rs * w2.y);
  ov[6] = (__bf16)((b.z - mu) * rs * w2.z);
  ov[7] = (__bf16)((b.w - mu) * rs * w2.w);
  *(bf16x8*)(out + (size_t)row * EMB + t * 8) = ov;
}

// ---------------- GEMM: C[M,N] = A[M,K] * B[N,K]^T  (both row-major, bf16 in, f32 acc) ----
// EPI: 0 = store bf16; 1 = store f32 (resid + acc); 2 = store bf16 gelu(acc); 3 = f32 C += acc
template <int EPI>
__global__ __launch_bounds__(256) void gemm_bt(const __bf16* __restrict__ A,
                                               const __bf16* __restrict__ B,
                                               void* __restrict__ Cv,
                                               const float* __restrict__ resid,
                                               int M, int N, int K) {
  __shared__ __bf16 As[128 * 32];
  __shared__ __bf16 Bs[128 * 32];
  const int t = threadIdx.x, w = t >> 6, l = t & 63;
  const int m0 = blockIdx.y * 128, n0 = blockIdx.x * 128;
  const int wr = w >> 1, wc = w & 1;            // wave's 64x64 quadrant
  const int fr = l & 15, fkb = (l >> 4) * 8;    // fragment row / k-offset
  const int srow = w * 16 + (l >> 2);           // staging row within 64-row round
  const int scol = (l & 3) * 8;                 // staging col (elements)

  f32x4 acc[4][4] = {};

  for (int k0 = 0; k0 < K; k0 += 32) {
    if (k0) __syncthreads();
    #pragma unroll
    for (int r = 0; r < 2; r++) {
      async_copy16(As + r * 2048 + w * 512,
                   A + (size_t)(m0 + r * 64 + srow) * K + k0 + scol);
      async_copy16(Bs + r * 2048 + w * 512,
                   B + (size_t)(n0 + r * 64 + srow) * K + k0 + scol);
    }
    __syncthreads();

    bf16x8 af[4], bfr[4];
    #pragma unroll
    for (int m = 0; m < 4; m++)
      af[m] = *(const bf16x8*)&As[(wr * 64 + m * 16 + fr) * 32 + fkb];
    #pragma unroll
    for (int n = 0; n < 4; n++)
      bfr[n] = *(const bf16x8*)&Bs[(wc * 64 + n * 16 + fr) * 32 + fkb];
    #pragma unroll
    for (int m = 0; m < 4; m++)
      #pragma unroll
      for (int n = 0; n < 4; n++)
        acc[m][n] = __builtin_amdgcn_mfma_f32_16x16x32_bf16(af[m], bfr[n], acc[m][n], 0, 0, 0);
  }

  #pragma unroll
  for (int m = 0; m < 4; m++)
    #pragma unroll
    for (int n = 0; n < 4; n++)
      #pragma unroll
      for (int j = 0; j < 4; j++) {
        int orow = m0 + wr * 64 + m * 16 + (l >> 4) * 4 + j;
        int ocol = n0 + wc * 64 + n * 16 + (l & 15);
        size_t idx = (size_t)orow * N + ocol;
        float v = acc[m][n][j];
        if (EPI == 0) {
          ((__bf16*)Cv)[idx] = (__bf16)v;
        } else if (EPI == 1) {
          ((float*)Cv)[idx] = resid[idx] + v;
        } else if (EPI == 2) {
          ((__bf16*)Cv)[idx] = (__bf16)gelu_tanh(v);
        } else {
          ((float*)Cv)[idx] += v;
        }
      }
}

// ---------------- Flash attention (causal), bf16 in/out, fp32 online softmax ----------------
// grid: (S/64, H). Block 256 = 4 waves; wave w owns q-rows [qb*64 + w*16, +16).
__global__ __launch_bounds__(256) void attn_kernel(const __bf16* __restrict__ qkv,
                                                   __bf16* __restrict__ out) {
  __shared__ __bf16 Kt[64 * 128];   // K tile  [key][d]
  __shared__ __bf16 Vt[128 * 64];   // V^T     [d][key]
  __shared__ __bf16 Pb[4][16 * 64]; // per-wave P [q][key]

  const int qb = blockIdx.x, h = blockIdx.y;
  const int t = threadIdx.x, w = t >> 6, l = t & 63;
  const int fr = l & 15, fkb = (l >> 4) * 8;
  const int q0 = qb * 64 + w * 16;
  const float scale = 0.08838834764831845f; // 1/sqrt(128)

  // Q fragments (held in registers for the whole kernel)
  bf16x8 qf[4];
  #pragma unroll
  for (int kc = 0; kc < 4; kc++)
    qf[kc] = *(const bf16x8*)&qkv[(size_t)(q0 + fr) * (3 * EMB) + h * HD + kc * 32 + fkb];

  f32x4 o[8] = {};
  float mrun[4] = {-1e30f, -1e30f, -1e30f, -1e30f};
  float lsum[4] = {0.f, 0.f, 0.f, 0.f};

  const int krow = w * 4 + (l >> 4);
  const int kc0  = (l & 15) * 8;

  for (int t0 = 0; t0 <= qb * 64; t0 += 64) {
    if (t0) __syncthreads();
    // stage K tile via global_load_lds (linear [64][128])
    #pragma unroll
    for (int r = 0; r < 4; r++)
      async_copy16(Kt + r * 2048 + w * 512,
                   qkv + (size_t)(t0 + r * 16 + krow) * (3 * EMB) + EMB + h * HD + kc0);
    // stage V transposed (reg-staged)
    #pragma unroll
    for (int i = 0; i < 4; i++) {
      int idx = i * 256 + t;            // 1024 chunks of 8
      int vrow = idx >> 4;              // key 0..63
      int c0 = (idx & 15) * 8;          // d
      bf16x8 v = *(const bf16x8*)&qkv[(size_t)(t0 + vrow) * (3 * EMB) + 2 * EMB + h * HD + c0];
      #pragma unroll
      for (int j = 0; j < 8; j++) Vt[(c0 + j) * 64 + vrow] = v[j];
    }
    __syncthreads();

    // QK^T: scores s[n] for 4 key-blocks of 16
    f32x4 s[4] = {};
    #pragma unroll
    for (int n = 0; n < 4; n++)
      #pragma unroll
      for (int kc = 0; kc < 4; kc++) {
        bf16x8 kf = *(const bf16x8*)&Kt[(n * 16 + fr) * 128 + kc * 32 + fkb];
        s[n] = __builtin_amdgcn_mfma_f32_16x16x32_bf16(qf[kc], kf, s[n], 0, 0, 0);
      }
    // scale + causal mask
    #pragma unroll
    for (int n = 0; n < 4; n++)
      #pragma unroll
      for (int j = 0; j < 4; j++) {
        int tcol = t0 + n * 16 + (l & 15);
        int qrow = q0 + (l >> 4) * 4 + j;
        float v = s[n][j] * scale;
        s[n][j] = (tcol > qrow) ? -1e30f : v;
      }
    // row max (over 4 n-blocks and 16 lanes of the column group)
    float pm[4];
    #pragma unroll
    for (int j = 0; j < 4; j++) {
      pm[j] = fmaxf(fmaxf(s[0][j], s[1][j]), fmaxf(s[2][j], s[3][j]));
      #pragma unroll
      for (int off = 1; off < 16; off <<= 1) pm[j] = fmaxf(pm[j], __shfl_xor(pm[j], off));
    }
    float factor[4];
    #pragma unroll
    for (int j = 0; j < 4; j++) {
      float mn = fmaxf(mrun[j], pm[j]);
      factor[j] = __expf(mrun[j] - mn);
      mrun[j] = mn;
    }
    // p = exp(s - m), row sums
    float rs[4] = {0.f, 0.f, 0.f, 0.f};
    #pragma unroll
    for (int n = 0; n < 4; n++)
      #pragma unroll
      for (int j = 0; j < 4; j++) {
        float p = __expf(s[n][j] - mrun[j]);
        s[n][j] = p;
        rs[j] += p;
      }
    #pragma unroll
    for (int j = 0; j < 4; j++) {
      #pragma unroll
      for (int off = 1; off < 16; off <<= 1) rs[j] += __shfl_xor(rs[j], off);
      lsum[j] = lsum[j] * factor[j] + rs[j];
    }
    #pragma unroll
    for (int b = 0; b < 8; b++)
      #pragma unroll
      for (int j = 0; j < 4; j++) o[b][j] *= factor[j];
    // write P (bf16) to this wave's LDS buffer: P[q 0..15][key 0..63]
    #pragma unroll
    for (int n = 0; n < 4; n++)
      #pragma unroll
      for (int j = 0; j < 4; j++)
        Pb[w][((l >> 4) * 4 + j) * 64 + n * 16 + (l & 15)] = (__bf16)s[n][j];
    __syncthreads();
    // PV: O[16 q][128 d] += P[16x64] * V[64x128]
    bf16x8 pf[2];
    #pragma unroll
    for (int kc = 0; kc < 2; kc++)
      pf[kc] = *(const bf16x8*)&Pb[w][fr * 64 + kc * 32 + fkb];
    #pragma unroll
    for (int b = 0; b < 8; b++)
      #pragma unroll
      for (int kc = 0; kc < 2; kc++) {
        bf16x8 vf = *(const bf16x8*)&Vt[(b * 16 + fr) * 64 + kc * 32 + fkb];
        o[b] = __builtin_amdgcn_mfma_f32_16x16x32_bf16(pf[kc], vf, o[b], 0, 0, 0);
      }
  }

  // normalize + write out [S, E] at columns h*128..
  float rcp[4];
  #pragma unroll
  for (int j = 0; j < 4; j++) rcp[j] = 1.0f / lsum[j];
  #pragma unroll
  for (int b = 0; b < 8; b++)
    #pragma unroll
    for (int j = 0; j < 4; j++) {
      int qrow = q0 + (l >> 4) * 4 + j;
      out[(size_t)qrow * EMB + h * HD + b * 16 + (l & 15)] = (__bf16)(o[b][j] * rcp[j]);
    }
}

// ---------------- launch ----------------
extern "C" void kernel_launch(void* const* d_in, const int* in_sizes, int n_in,
                              void* d_out, int out_size, void* d_ws, size_t ws_size,
                              hipStream_t stream) {
  const float* x     = (const float*)d_in[0];
  const float* ln1w  = (const float*)d_in[1];
  const float* ln2w  = (const float*)d_in[2];
  const float* wattn = (const float*)d_in[3];
  const float* wproja= (const float*)d_in[4];
  const float* wfc   = (const float*)d_in[5];
  const float* wprojf= (const float*)d_in[6];
  float* out = (float*)d_out;
  char* ws = (char*)d_ws;

  // workspace layout (bytes)
  __bf16* wattn_b  = (__bf16*)(ws);                 // 3E*E   = 12582912 el
  __bf16* wproja_b = (__bf16*)(ws + 25165824);      // E*E    =  4194304 el
  __bf16* wfc_b    = (__bf16*)(ws + 33554432);      // 4E*E   = 16777216 el
  __bf16* wprojf_b = (__bf16*)(ws + 67108864);      // E*4E   = 16777216 el
  __bf16* h_b      = (__bf16*)(ws + 100663296);     // S*E
  __bf16* qkv_b    = (__bf16*)(ws + 109051904);     // S*3E
  __bf16* attn_b   = (__bf16*)(ws + 134217728);     // S*E
  __bf16* f1_b     = (__bf16*)(ws + 142606336);     // S*4E
  // total = 176160768 bytes

  // weight casts
  cast_kernel<<<12288, 256, 0, stream>>>(wattn,  wattn_b,  12582912);
  cast_kernel<<<4096,  256, 0, stream>>>(wproja, wproja_b, 4194304);
  cast_kernel<<<16384, 256, 0, stream>>>(wfc,    wfc_b,    16777216);
  cast_kernel<<<16384, 256, 0, stream>>>(wprojf, wprojf_b, 16777216);

  // LN1
  ln_kernel<<<S_LEN, 256, 0, stream>>>(x, ln1w, h_b);
  // QKV: [2048, 6144]
  gemm_bt<0><<<dim3(48, 16), 256, 0, stream>>>(h_b, wattn_b, qkv_b, nullptr, S_LEN, 3 * EMB, EMB);
  // attention
  attn_kernel<<<dim3(S_LEN / 64, NH), 256, 0, stream>>>(qkv_b, attn_b);
  // attn proj + residual -> d_out (f32)
  gemm_bt<1><<<dim3(16, 16), 256, 0, stream>>>(attn_b, wproja_b, out, x, S_LEN, EMB, EMB);
  // LN2 (reads d_out)
  ln_kernel<<<S_LEN, 256, 0, stream>>>(out, ln2w, h_b);
  // FC + GELU: [2048, 8192]
  gemm_bt<2><<<dim3(64, 16), 256, 0, stream>>>(h_b, wfc_b, f1_b, nullptr, S_LEN, 4 * EMB, EMB);
  // FFN proj, accumulate into d_out
  gemm_bt<3><<<dim3(16, 16), 256, 0, stream>>>(f1_b, wprojf_b, out, nullptr, S_LEN, EMB, 4 * EMB);
}

// Round 3
// 531.248 us; speedup vs baseline: 1.3235x; 1.3235x over previous
//
#include <hip/hip_runtime.h>
#include <hip/hip_bf16.h>

// S=2048, E=2048, H=16, D=128
#define S_LEN 2048
#define EMB   2048
#define NH    16
#define HD    128

typedef __bf16 bf16x8 __attribute__((ext_vector_type(8)));
typedef __bf16 bf16x4 __attribute__((ext_vector_type(4)));
typedef float  f32x4  __attribute__((ext_vector_type(4)));
typedef short  s16x4  __attribute__((ext_vector_type(4)));

__device__ __forceinline__ void async_copy16(void* lds, const void* g) {
  __builtin_amdgcn_global_load_lds((__attribute__((address_space(1))) void*)(void*)g,
                                   (__attribute__((address_space(3))) void*)lds, 16, 0, 0);
}

__device__ __forceinline__ unsigned lds_addr(const void* p) {
  return (unsigned)(uintptr_t)(const __attribute__((address_space(3))) char*)p;
}

__device__ __forceinline__ s16x4 tr16(unsigned addr) {
  s16x4 d;
  asm volatile("ds_read_b64_tr_b16 %0, %1" : "=v"(d) : "v"(addr));
  return d;
}

__device__ __forceinline__ float gelu_tanh(float x) {
  float x3 = x * x * x;
  float t  = 0.7978845608028654f * (x + 0.044715f * x3);
  float th = 1.0f - 2.0f / (__expf(2.0f * t) + 1.0f);
  return 0.5f * x * (1.0f + th);
}

// ---------------- fp32 -> bf16 cast (weights) ----------------
__global__ __launch_bounds__(256) void cast_kernel(const float* __restrict__ in,
                                                   __bf16* __restrict__ out, int n) {
  int i = (blockIdx.x * 256 + threadIdx.x) * 4;
  if (i >= n) return;
  float4 v = *(const float4*)(in + i);
  bf16x4 o;
  o[0] = (__bf16)v.x; o[1] = (__bf16)v.y; o[2] = (__bf16)v.z; o[3] = (__bf16)v.w;
  *(bf16x4*)(out + i) = o;
}

// ---------------- LayerNorm ----------------
__global__ __launch_bounds__(256) void ln_kernel(const float* __restrict__ x,
                                                 const float* __restrict__ w,
                                                 __bf16* __restrict__ out) {
  int row = blockIdx.x;
  int t = threadIdx.x;
  const float* xr = x + (size_t)row * EMB;
  float4 a = *(const float4*)(xr + t * 8);
  float4 b = *(const float4*)(xr + t * 8 + 4);
  float s  = a.x + a.y + a.z + a.w + b.x + b.y + b.z + b.w;
  float sq = a.x*a.x + a.y*a.y + a.z*a.z + a.w*a.w + b.x*b.x + b.y*b.y + b.z*b.z + b.w*b.w;
  #pragma unroll
  for (int o = 32; o > 0; o >>= 1) { s += __shfl_xor(s, o); sq += __shfl_xor(sq, o); }
  __shared__ float red[8];
  if ((t & 63) == 0) { red[t >> 6] = s; red[(t >> 6) + 4] = sq; }
  __syncthreads();
  s  = red[0] + red[1] + red[2] + red[3];
  sq = red[4] + red[5] + red[6] + red[7];
  float mu  = s * (1.0f / EMB);
  float var = sq * (1.0f / EMB) - mu * mu;
  float rs  = rsqrtf(var + 1e-5f);
  float4 w1 = *(const float4*)(w + t * 8);
  float4 w2 = *(const float4*)(w + t * 8 + 4);
  bf16x8 ov;
  ov[0] = (__bf16)((a.x - mu) * rs * w1.x);
  ov[1] = (__bf16)((a.y - mu) * rs * w1.y);
  ov[2] = (__bf16)((a.z - mu) * rs * w1.z);
  ov[3] = (__bf16)((a.w - mu) * rs * w1.w);
  ov[4] = (__bf16)((b.x - mu) * rs * w2.x);
  ov[5] = (__bf16)((b.y - mu) * rs * w2.y);
  ov[6] = (__bf16)((b.z - mu) * rs * w2.z);
  ov[7] = (__bf16)((b.w - mu) * rs * w2.w);
  *(bf16x8*)(out + (size_t)row * EMB + t * 8) = ov;
}

// ---------------- GEMM: C[M,N] = A[M,K] * B[N,K]^T ----------------
template <int EPI>
__global__ __launch_bounds__(256) void gemm_bt(const __bf16* __restrict__ A,
                                               const __bf16* __restrict__ B,
                                               void* __restrict__ Cv,
                                               const float* __restrict__ resid,
                                               int M, int N, int K) {
  __shared__ __bf16 As[128 * 32];
  __shared__ __bf16 Bs[128 * 32];
  const int t = threadIdx.x, w = t >> 6, l = t & 63;
  const int m0 = blockIdx.y * 128, n0 = blockIdx.x * 128;
  const int wr = w >> 1, wc = w & 1;
  const int fr = l & 15, fkb = (l >> 4) * 8;
  const int srow = w * 16 + (l >> 2);
  const int scol = (l & 3) * 8;

  f32x4 acc[4][4] = {};

  for (int k0 = 0; k0 < K; k0 += 32) {
    if (k0) __syncthreads();
    #pragma unroll
    for (int r = 0; r < 2; r++) {
      async_copy16(As + r * 2048 + w * 512,
                   A + (size_t)(m0 + r * 64 + srow) * K + k0 + scol);
      async_copy16(Bs + r * 2048 + w * 512,
                   B + (size_t)(n0 + r * 64 + srow) * K + k0 + scol);
    }
    __syncthreads();

    bf16x8 af[4], bfr[4];
    #pragma unroll
    for (int m = 0; m < 4; m++)
      af[m] = *(const bf16x8*)&As[(wr * 64 + m * 16 + fr) * 32 + fkb];
    #pragma unroll
    for (int n = 0; n < 4; n++)
      bfr[n] = *(const bf16x8*)&Bs[(wc * 64 + n * 16 + fr) * 32 + fkb];
    #pragma unroll
    for (int m = 0; m < 4; m++)
      #pragma unroll
      for (int n = 0; n < 4; n++)
        acc[m][n] = __builtin_amdgcn_mfma_f32_16x16x32_bf16(af[m], bfr[n], acc[m][n], 0, 0, 0);
  }

  #pragma unroll
  for (int m = 0; m < 4; m++)
    #pragma unroll
    for (int n = 0; n < 4; n++)
      #pragma unroll
      for (int j = 0; j < 4; j++) {
        int orow = m0 + wr * 64 + m * 16 + (l >> 4) * 4 + j;
        int ocol = n0 + wc * 64 + n * 16 + (l & 15);
        size_t idx = (size_t)orow * N + ocol;
        float v = acc[m][n][j];
        if (EPI == 0) {
          ((__bf16*)Cv)[idx] = (__bf16)v;
        } else if (EPI == 1) {
          ((float*)Cv)[idx] = resid[idx] + v;
        } else if (EPI == 2) {
          ((__bf16*)Cv)[idx] = (__bf16)gelu_tanh(v);
        } else {
          ((float*)Cv)[idx] += v;
        }
      }
}

// ---------------- Flash attention (causal) ----------------
// 512 blocks; bid -> h = bid&15, idx = bid>>4, qb = idx<16 ? idx : 47-idx
// so co-resident block pairs (idx, idx+16) sum to constant 33 tile-steps.
// K: XOR-chunk-swizzled [64][128]; V: subtiled [key/4][d/16][4][16] for tr-reads.
// Double-buffered K/V staging via global_load_lds issued right after the barrier.
__global__ __launch_bounds__(256) void attn_kernel(const __bf16* __restrict__ qkv,
                                                   __bf16* __restrict__ out) {
  __shared__ __bf16 Kt[2][64 * 128];
  __shared__ __bf16 Vt[2][64 * 128];
  __shared__ __bf16 Pb[4][16 * 64];

  const int bid = blockIdx.x;
  const int h = bid & 15;
  const int idx = bid >> 4;
  const int qb = (idx < 16) ? idx : 47 - idx;

  const int t = threadIdx.x, w = t >> 6, l = t & 63;
  const int g = l >> 4, fr = l & 15;
  const int fkb = g * 8;
  const int q0 = qb * 64 + w * 16;
  const float scale = 0.08838834764831845f; // 1/sqrt(128)

  // staging source coordinates
  const int krow = w * 4 + g;                    // row within each 16-row round
  const int kchunk = fr ^ (krow & 7);            // pre-swizzled global chunk for K
  const int vkey = (l >> 1) & 3;                 // V: key within 4-key group
  const int vd0  = (l >> 3) * 16 + (l & 1) * 8;  // V: d offset

  const size_t row3E = (size_t)(3 * EMB);
  const __bf16* Kg = qkv + EMB + h * HD;
  const __bf16* Vg = qkv + 2 * EMB + h * HD;

  // Q fragments (registers, whole kernel)
  bf16x8 qf[4];
  #pragma unroll
  for (int kc = 0; kc < 4; kc++)
    qf[kc] = *(const bf16x8*)&qkv[(size_t)(q0 + fr) * row3E + h * HD + kc * 32 + fkb];

  f32x4 o[8] = {};
  float mrun[4] = {-1e30f, -1e30f, -1e30f, -1e30f};
  float lsum[4] = {0.f, 0.f, 0.f, 0.f};

  // tr-read slot address: lane fr selects b64 slot fr of the 4x16 subtile
  // (cooperative 16-lane transpose; slot stride is 8 BYTES)
  const unsigned vtrb[2] = { lds_addr(&Vt[0][0]) + g * 2048 + fr * 8,
                             lds_addr(&Vt[1][0]) + g * 2048 + fr * 8 };

  auto stage = [&](int buf, int it) {
    const int t0 = it * 64;
    #pragma unroll
    for (int r = 0; r < 4; r++) {
      async_copy16(&Kt[buf][r * 2048 + w * 512],
                   Kg + (size_t)(t0 + r * 16 + krow) * row3E + kchunk * 8);
      async_copy16(&Vt[buf][(r * 4 + w) * 512],
                   Vg + (size_t)(t0 + r * 16 + w * 4 + vkey) * row3E + vd0);
    }
  };

  const int nt = qb + 1;
  stage(0, 0);
  int cur = 0;

  for (int it = 0; it < nt; it++) {
    __syncthreads();                     // staging of buf[cur] complete
    if (it + 1 < nt) stage(cur ^ 1, it + 1);  // prefetch hides under softmax+PV
    const int t0 = it * 64;

    // QK^T (swizzled K reads)
    f32x4 s[4] = {};
    #pragma unroll
    for (int n = 0; n < 4; n++)
      #pragma unroll
      for (int kc = 0; kc < 4; kc++) {
        bf16x8 kf = *(const bf16x8*)&Kt[cur][(n * 16 + fr) * 128 +
                                            (((kc * 4 + g) ^ (fr & 7)) << 3)];
        s[n] = __builtin_amdgcn_mfma_f32_16x16x32_bf16(qf[kc], kf, s[n], 0, 0, 0);
      }
    // scale + causal mask
    #pragma unroll
    for (int n = 0; n < 4; n++)
      #pragma unroll
      for (int j = 0; j < 4; j++) {
        int tcol = t0 + n * 16 + fr;
        int qrow = q0 + g * 4 + j;
        float v = s[n][j] * scale;
        s[n][j] = (tcol > qrow) ? -1e30f : v;
      }
    // online softmax
    float pm[4];
    #pragma unroll
    for (int j = 0; j < 4; j++) {
      pm[j] = fmaxf(fmaxf(s[0][j], s[1][j]), fmaxf(s[2][j], s[3][j]));
      #pragma unroll
      for (int off = 1; off < 16; off <<= 1) pm[j] = fmaxf(pm[j], __shfl_xor(pm[j], off));
    }
    float factor[4];
    #pragma unroll
    for (int j = 0; j < 4; j++) {
      float mn = fmaxf(mrun[j], pm[j]);
      factor[j] = __expf(mrun[j] - mn);
      mrun[j] = mn;
    }
    float rs[4] = {0.f, 0.f, 0.f, 0.f};
    #pragma unroll
    for (int n = 0; n < 4; n++)
      #pragma unroll
      for (int j = 0; j < 4; j++) {
        float p = __expf(s[n][j] - mrun[j]);
        s[n][j] = p;
        rs[j] += p;
      }
    #pragma unroll
    for (int j = 0; j < 4; j++) {
      #pragma unroll
      for (int off = 1; off < 16; off <<= 1) rs[j] += __shfl_xor(rs[j], off);
      lsum[j] = lsum[j] * factor[j] + rs[j];
    }
    #pragma unroll
    for (int b = 0; b < 8; b++)
      #pragma unroll
      for (int j = 0; j < 4; j++) o[b][j] *= factor[j];

    // P -> LDS (bf16), XOR-chunk-swizzled scalar writes
    #pragma unroll
    for (int n = 0; n < 4; n++)
      #pragma unroll
      for (int j = 0; j < 4; j++) {
        int q   = g * 4 + j;
        int key = n * 16 + fr;
        int cs  = (key >> 3) ^ (q & 7);
        Pb[w][q * 64 + cs * 8 + (key & 7)] = (__bf16)s[n][j];
      }

    // P fragments (swizzled b128 reads; compiler orders the LDS RAW)
    bf16x8 pf[2];
    #pragma unroll
    for (int kc = 0; kc < 2; kc++)
      pf[kc] = *(const bf16x8*)&Pb[w][fr * 64 + (((kc * 4 + g) ^ (fr & 7)) << 3)];

    // PV via hardware transpose reads of subtiled V
    const unsigned vtr = vtrb[cur];
    #pragma unroll
    for (int b = 0; b < 8; b++) {
      s16x4 t00 = tr16(vtr + b * 128);
      s16x4 t01 = tr16(vtr + b * 128 + 1024);
      s16x4 t10 = tr16(vtr + b * 128 + 8192);
      s16x4 t11 = tr16(vtr + b * 128 + 8192 + 1024);
      asm volatile("s_waitcnt lgkmcnt(0)");
      __builtin_amdgcn_sched_barrier(0);
      union { s16x4 hh[2]; bf16x8 v; } u0, u1;
      u0.hh[0] = t00; u0.hh[1] = t01;
      u1.hh[0] = t10; u1.hh[1] = t11;
      o[b] = __builtin_amdgcn_mfma_f32_16x16x32_bf16(pf[0], u0.v, o[b], 0, 0, 0);
      o[b] = __builtin_amdgcn_mfma_f32_16x16x32_bf16(pf[1], u1.v, o[b], 0, 0, 0);
    }
    cur ^= 1;
  }

  // normalize + write
  float rcp[4];
  #pragma unroll
  for (int j = 0; j < 4; j++) rcp[j] = 1.0f / lsum[j];
  #pragma unroll
  for (int b = 0; b < 8; b++)
    #pragma unroll
    for (int j = 0; j < 4; j++) {
      int qrow = q0 + g * 4 + j;
      out[(size_t)qrow * EMB + h * HD + b * 16 + fr] = (__bf16)(o[b][j] * rcp[j]);
    }
}

// ---------------- launch ----------------
extern "C" void kernel_launch(void* const* d_in, const int* in_sizes, int n_in,
                              void* d_out, int out_size, void* d_ws, size_t ws_size,
                              hipStream_t stream) {
  const float* x     = (const float*)d_in[0];
  const float* ln1w  = (const float*)d_in[1];
  const float* ln2w  = (const float*)d_in[2];
  const float* wattn = (const float*)d_in[3];
  const float* wproja= (const float*)d_in[4];
  const float* wfc   = (const float*)d_in[5];
  const float* wprojf= (const float*)d_in[6];
  float* out = (float*)d_out;
  char* ws = (char*)d_ws;

  __bf16* wattn_b  = (__bf16*)(ws);                 // 3E*E
  __bf16* wproja_b = (__bf16*)(ws + 25165824);      // E*E
  __bf16* wfc_b    = (__bf16*)(ws + 33554432);      // 4E*E
  __bf16* wprojf_b = (__bf16*)(ws + 67108864);      // E*4E
  __bf16* h_b      = (__bf16*)(ws + 100663296);     // S*E
  __bf16* qkv_b    = (__bf16*)(ws + 109051904);     // S*3E
  __bf16* attn_b   = (__bf16*)(ws + 134217728);     // S*E
  __bf16* f1_b     = (__bf16*)(ws + 142606336);     // S*4E

  cast_kernel<<<12288, 256, 0, stream>>>(wattn,  wattn_b,  12582912);
  cast_kernel<<<4096,  256, 0, stream>>>(wproja, wproja_b, 4194304);
  cast_kernel<<<16384, 256, 0, stream>>>(wfc,    wfc_b,    16777216);
  cast_kernel<<<16384, 256, 0, stream>>>(wprojf, wprojf_b, 16777216);

  ln_kernel<<<S_LEN, 256, 0, stream>>>(x, ln1w, h_b);
  gemm_bt<0><<<dim3(48, 16), 256, 0, stream>>>(h_b, wattn_b, qkv_b, nullptr, S_LEN, 3 * EMB, EMB);
  attn_kernel<<<dim3(512), 256, 0, stream>>>(qkv_b, attn_b);
  gemm_bt<1><<<dim3(16, 16), 256, 0, stream>>>(attn_b, wproja_b, out, x, S_LEN, EMB, EMB);
  ln_kernel<<<S_LEN, 256, 0, stream>>>(out, ln2w, h_b);
  gemm_bt<2><<<dim3(64, 16), 256, 0, stream>>>(h_b, wfc_b, f1_b, nullptr, S_LEN, 4 * EMB, EMB);
  gemm_bt<3><<<dim3(16, 16), 256, 0, stream>>>(f1_b, wprojf_b, out, nullptr, S_LEN, EMB, 4 * EMB);
}

// Round 4
// 503.010 us; speedup vs baseline: 1.3978x; 1.0561x over previous
//
#include <hip/hip_runtime.h>
#include <hip/hip_bf16.h>

// S=2048, E=2048, H=16, D=128
#define S_LEN 2048
#define EMB   2048
#define NH    16
#define HD    128

typedef __bf16 bf16x8 __attribute__((ext_vector_type(8)));
typedef __bf16 bf16x4 __attribute__((ext_vector_type(4)));
typedef float  f32x4  __attribute__((ext_vector_type(4)));
typedef short  s16x4  __attribute__((ext_vector_type(4)));

__device__ __forceinline__ void async_copy16(void* lds, const void* g) {
  __builtin_amdgcn_global_load_lds((__attribute__((address_space(1))) void*)(void*)g,
                                   (__attribute__((address_space(3))) void*)lds, 16, 0, 0);
}

__device__ __forceinline__ unsigned lds_addr(const void* p) {
  return (unsigned)(uintptr_t)(const __attribute__((address_space(3))) char*)p;
}

__device__ __forceinline__ s16x4 tr16(unsigned addr) {
  s16x4 d;
  asm volatile("ds_read_b64_tr_b16 %0, %1" : "=v"(d) : "v"(addr));
  return d;
}

__device__ __forceinline__ float gelu_tanh(float x) {
  float x3 = x * x * x;
  float t  = 0.7978845608028654f * (x + 0.044715f * x3);
  float th = 1.0f - 2.0f / (__expf(2.0f * t) + 1.0f);
  return 0.5f * x * (1.0f + th);
}

// ---------------- fp32 -> bf16 cast (weights) ----------------
__global__ __launch_bounds__(256) void cast_kernel(const float* __restrict__ in,
                                                   __bf16* __restrict__ out, int n) {
  int i = (blockIdx.x * 256 + threadIdx.x) * 4;
  if (i >= n) return;
  float4 v = *(const float4*)(in + i);
  bf16x4 o;
  o[0] = (__bf16)v.x; o[1] = (__bf16)v.y; o[2] = (__bf16)v.z; o[3] = (__bf16)v.w;
  *(bf16x4*)(out + i) = o;
}

// ---------------- LayerNorm ----------------
__global__ __launch_bounds__(256) void ln_kernel(const float* __restrict__ x,
                                                 const float* __restrict__ w,
                                                 __bf16* __restrict__ out) {
  int row = blockIdx.x;
  int t = threadIdx.x;
  const float* xr = x + (size_t)row * EMB;
  float4 a = *(const float4*)(xr + t * 8);
  float4 b = *(const float4*)(xr + t * 8 + 4);
  float s  = a.x + a.y + a.z + a.w + b.x + b.y + b.z + b.w;
  float sq = a.x*a.x + a.y*a.y + a.z*a.z + a.w*a.w + b.x*b.x + b.y*b.y + b.z*b.z + b.w*b.w;
  #pragma unroll
  for (int o = 32; o > 0; o >>= 1) { s += __shfl_xor(s, o); sq += __shfl_xor(sq, o); }
  __shared__ float red[8];
  if ((t & 63) == 0) { red[t >> 6] = s; red[(t >> 6) + 4] = sq; }
  __syncthreads();
  s  = red[0] + red[1] + red[2] + red[3];
  sq = red[4] + red[5] + red[6] + red[7];
  float mu  = s * (1.0f / EMB);
  float var = sq * (1.0f / EMB) - mu * mu;
  float rs  = rsqrtf(var + 1e-5f);
  float4 w1 = *(const float4*)(w + t * 8);
  float4 w2 = *(const float4*)(w + t * 8 + 4);
  bf16x8 ov;
  ov[0] = (__bf16)((a.x - mu) * rs * w1.x);
  ov[1] = (__bf16)((a.y - mu) * rs * w1.y);
  ov[2] = (__bf16)((a.z - mu) * rs * w1.z);
  ov[3] = (__bf16)((a.w - mu) * rs * w1.w);
  ov[4] = (__bf16)((b.x - mu) * rs * w2.x);
  ov[5] = (__bf16)((b.y - mu) * rs * w2.y);
  ov[6] = (__bf16)((b.z - mu) * rs * w2.z);
  ov[7] = (__bf16)((b.w - mu) * rs * w2.w);
  *(bf16x8*)(out + (size_t)row * EMB + t * 8) = ov;
}

// ---------------- GEMM: C[M,N] = A[M,K] * B[N,K]^T ----------------
// EPI: 0 = store bf16; 2 = store bf16 gelu(acc); 4 = atomicAdd f32 (split-K)
// Each blockIdx.z owns K-slice [z*Ksl, (z+1)*Ksl).
template <int EPI>
__global__ __launch_bounds__(256) void gemm_bt(const __bf16* __restrict__ A,
                                               const __bf16* __restrict__ B,
                                               void* __restrict__ Cv,
                                               int M, int N, int K, int Ksl) {
  __shared__ __bf16 As[128 * 32];
  __shared__ __bf16 Bs[128 * 32];
  const int t = threadIdx.x, w = t >> 6, l = t & 63;
  const int m0 = blockIdx.y * 128, n0 = blockIdx.x * 128;
  const int wr = w >> 1, wc = w & 1;
  const int fr = l & 15, fkb = (l >> 4) * 8;
  const int srow = w * 16 + (l >> 2);
  const int scol = (l & 3) * 8;
  const int kb = blockIdx.z * Ksl, ke = kb + Ksl;

  f32x4 acc[4][4] = {};

  for (int k0 = kb; k0 < ke; k0 += 32) {
    if (k0 != kb) __syncthreads();
    #pragma unroll
    for (int r = 0; r < 2; r++) {
      async_copy16(As + r * 2048 + w * 512,
                   A + (size_t)(m0 + r * 64 + srow) * K + k0 + scol);
      async_copy16(Bs + r * 2048 + w * 512,
                   B + (size_t)(n0 + r * 64 + srow) * K + k0 + scol);
    }
    __syncthreads();

    bf16x8 af[4], bfr[4];
    #pragma unroll
    for (int m = 0; m < 4; m++)
      af[m] = *(const bf16x8*)&As[(wr * 64 + m * 16 + fr) * 32 + fkb];
    #pragma unroll
    for (int n = 0; n < 4; n++)
      bfr[n] = *(const bf16x8*)&Bs[(wc * 64 + n * 16 + fr) * 32 + fkb];
    #pragma unroll
    for (int m = 0; m < 4; m++)
      #pragma unroll
      for (int n = 0; n < 4; n++)
        acc[m][n] = __builtin_amdgcn_mfma_f32_16x16x32_bf16(af[m], bfr[n], acc[m][n], 0, 0, 0);
  }

  #pragma unroll
  for (int m = 0; m < 4; m++)
    #pragma unroll
    for (int n = 0; n < 4; n++)
      #pragma unroll
      for (int j = 0; j < 4; j++) {
        int orow = m0 + wr * 64 + m * 16 + (l >> 4) * 4 + j;
        int ocol = n0 + wc * 64 + n * 16 + (l & 15);
        size_t idx = (size_t)orow * N + ocol;
        float v = acc[m][n][j];
        if (EPI == 0) {
          ((__bf16*)Cv)[idx] = (__bf16)v;
        } else if (EPI == 2) {
          ((__bf16*)Cv)[idx] = (__bf16)gelu_tanh(v);
        } else {
          atomicAdd((float*)Cv + idx, v);
        }
      }
}

// ---------------- Flash attention (causal) ----------------
// 512 blocks; bid -> h = bid&15, idx = bid>>4, qb = idx<16 ? idx : 47-idx
// so co-resident block pairs (idx, idx+16) sum to constant 33 tile-steps.
// K: XOR-chunk-swizzled [64][128]; V: subtiled [key/4][d/16][4][16] for tr-reads.
// Double-buffered K/V staging via global_load_lds issued right after the barrier.
__global__ __launch_bounds__(256) void attn_kernel(const __bf16* __restrict__ qkv,
                                                   __bf16* __restrict__ out) {
  __shared__ __bf16 Kt[2][64 * 128];
  __shared__ __bf16 Vt[2][64 * 128];
  __shared__ __bf16 Pb[4][16 * 64];

  const int bid = blockIdx.x;
  const int h = bid & 15;
  const int idx = bid >> 4;
  const int qb = (idx < 16) ? idx : 47 - idx;

  const int t = threadIdx.x, w = t >> 6, l = t & 63;
  const int g = l >> 4, fr = l & 15;
  const int fkb = g * 8;
  const int q0 = qb * 64 + w * 16;
  const float scale = 0.08838834764831845f; // 1/sqrt(128)

  const int krow = w * 4 + g;
  const int kchunk = fr ^ (krow & 7);
  const int vkey = (l >> 1) & 3;
  const int vd0  = (l >> 3) * 16 + (l & 1) * 8;

  const size_t row3E = (size_t)(3 * EMB);
  const __bf16* Kg = qkv + EMB + h * HD;
  const __bf16* Vg = qkv + 2 * EMB + h * HD;

  bf16x8 qf[4];
  #pragma unroll
  for (int kc = 0; kc < 4; kc++)
    qf[kc] = *(const bf16x8*)&qkv[(size_t)(q0 + fr) * row3E + h * HD + kc * 32 + fkb];

  f32x4 o[8] = {};
  float mrun[4] = {-1e30f, -1e30f, -1e30f, -1e30f};
  float lsum[4] = {0.f, 0.f, 0.f, 0.f};

  const unsigned vtrb[2] = { lds_addr(&Vt[0][0]) + g * 2048 + fr * 8,
                             lds_addr(&Vt[1][0]) + g * 2048 + fr * 8 };

  auto stage = [&](int buf, int it) {
    const int t0 = it * 64;
    #pragma unroll
    for (int r = 0; r < 4; r++) {
      async_copy16(&Kt[buf][r * 2048 + w * 512],
                   Kg + (size_t)(t0 + r * 16 + krow) * row3E + kchunk * 8);
      async_copy16(&Vt[buf][(r * 4 + w) * 512],
                   Vg + (size_t)(t0 + r * 16 + w * 4 + vkey) * row3E + vd0);
    }
  };

  const int nt = qb + 1;
  stage(0, 0);
  int cur = 0;

  for (int it = 0; it < nt; it++) {
    __syncthreads();
    if (it + 1 < nt) stage(cur ^ 1, it + 1);
    const int t0 = it * 64;

    f32x4 s[4] = {};
    #pragma unroll
    for (int n = 0; n < 4; n++)
      #pragma unroll
      for (int kc = 0; kc < 4; kc++) {
        bf16x8 kf = *(const bf16x8*)&Kt[cur][(n * 16 + fr) * 128 +
                                            (((kc * 4 + g) ^ (fr & 7)) << 3)];
        s[n] = __builtin_amdgcn_mfma_f32_16x16x32_bf16(qf[kc], kf, s[n], 0, 0, 0);
      }
    #pragma unroll
    for (int n = 0; n < 4; n++)
      #pragma unroll
      for (int j = 0; j < 4; j++) {
        int tcol = t0 + n * 16 + fr;
        int qrow = q0 + g * 4 + j;
        float v = s[n][j] * scale;
        s[n][j] = (tcol > qrow) ? -1e30f : v;
      }
    float pm[4];
    #pragma unroll
    for (int j = 0; j < 4; j++) {
      pm[j] = fmaxf(fmaxf(s[0][j], s[1][j]), fmaxf(s[2][j], s[3][j]));
      #pragma unroll
      for (int off = 1; off < 16; off <<= 1) pm[j] = fmaxf(pm[j], __shfl_xor(pm[j], off));
    }
    float factor[4];
    #pragma unroll
    for (int j = 0; j < 4; j++) {
      float mn = fmaxf(mrun[j], pm[j]);
      factor[j] = __expf(mrun[j] - mn);
      mrun[j] = mn;
    }
    float rs[4] = {0.f, 0.f, 0.f, 0.f};
    #pragma unroll
    for (int n = 0; n < 4; n++)
      #pragma unroll
      for (int j = 0; j < 4; j++) {
        float p = __expf(s[n][j] - mrun[j]);
        s[n][j] = p;
        rs[j] += p;
      }
    #pragma unroll
    for (int j = 0; j < 4; j++) {
      #pragma unroll
      for (int off = 1; off < 16; off <<= 1) rs[j] += __shfl_xor(rs[j], off);
      lsum[j] = lsum[j] * factor[j] + rs[j];
    }
    #pragma unroll
    for (int b = 0; b < 8; b++)
      #pragma unroll
      for (int j = 0; j < 4; j++) o[b][j] *= factor[j];

    #pragma unroll
    for (int n = 0; n < 4; n++)
      #pragma unroll
      for (int j = 0; j < 4; j++) {
        int q   = g * 4 + j;
        int key = n * 16 + fr;
        int cs  = (key >> 3) ^ (q & 7);
        Pb[w][q * 64 + cs * 8 + (key & 7)] = (__bf16)s[n][j];
      }

    bf16x8 pf[2];
    #pragma unroll
    for (int kc = 0; kc < 2; kc++)
      pf[kc] = *(const bf16x8*)&Pb[w][fr * 64 + (((kc * 4 + g) ^ (fr & 7)) << 3)];

    const unsigned vtr = vtrb[cur];
    #pragma unroll
    for (int b = 0; b < 8; b++) {
      s16x4 t00 = tr16(vtr + b * 128);
      s16x4 t01 = tr16(vtr + b * 128 + 1024);
      s16x4 t10 = tr16(vtr + b * 128 + 8192);
      s16x4 t11 = tr16(vtr + b * 128 + 8192 + 1024);
      asm volatile("s_waitcnt lgkmcnt(0)");
      __builtin_amdgcn_sched_barrier(0);
      union { s16x4 hh[2]; bf16x8 v; } u0, u1;
      u0.hh[0] = t00; u0.hh[1] = t01;
      u1.hh[0] = t10; u1.hh[1] = t11;
      o[b] = __builtin_amdgcn_mfma_f32_16x16x32_bf16(pf[0], u0.v, o[b], 0, 0, 0);
      o[b] = __builtin_amdgcn_mfma_f32_16x16x32_bf16(pf[1], u1.v, o[b], 0, 0, 0);
    }
    cur ^= 1;
  }

  float rcp[4];
  #pragma unroll
  for (int j = 0; j < 4; j++) rcp[j] = 1.0f / lsum[j];
  #pragma unroll
  for (int b = 0; b < 8; b++)
    #pragma unroll
    for (int j = 0; j < 4; j++) {
      int qrow = q0 + g * 4 + j;
      out[(size_t)qrow * EMB + h * HD + b * 16 + fr] = (__bf16)(o[b][j] * rcp[j]);
    }
}

// ---------------- launch ----------------
extern "C" void kernel_launch(void* const* d_in, const int* in_sizes, int n_in,
                              void* d_out, int out_size, void* d_ws, size_t ws_size,
                              hipStream_t stream) {
  const float* x     = (const float*)d_in[0];
  const float* ln1w  = (const float*)d_in[1];
  const float* ln2w  = (const float*)d_in[2];
  const float* wattn = (const float*)d_in[3];
  const float* wproja= (const float*)d_in[4];
  const float* wfc   = (const float*)d_in[5];
  const float* wprojf= (const float*)d_in[6];
  float* out = (float*)d_out;
  char* ws = (char*)d_ws;

  __bf16* wattn_b  = (__bf16*)(ws);                 // 3E*E
  __bf16* wproja_b = (__bf16*)(ws + 25165824);      // E*E
  __bf16* wfc_b    = (__bf16*)(ws + 33554432);      // 4E*E
  __bf16* wprojf_b = (__bf16*)(ws + 67108864);      // E*4E
  __bf16* h_b      = (__bf16*)(ws + 100663296);     // S*E
  __bf16* qkv_b    = (__bf16*)(ws + 109051904);     // S*3E
  __bf16* attn_b   = (__bf16*)(ws + 134217728);     // S*E
  __bf16* f1_b     = (__bf16*)(ws + 142606336);     // S*4E

  cast_kernel<<<12288, 256, 0, stream>>>(wattn,  wattn_b,  12582912);
  cast_kernel<<<4096,  256, 0, stream>>>(wproja, wproja_b, 4194304);
  cast_kernel<<<16384, 256, 0, stream>>>(wfc,    wfc_b,    16777216);
  cast_kernel<<<16384, 256, 0, stream>>>(wprojf, wprojf_b, 16777216);

  ln_kernel<<<S_LEN, 256, 0, stream>>>(x, ln1w, h_b);
  // QKV: [2048, 6144]
  gemm_bt<0><<<dim3(48, 16), 256, 0, stream>>>(h_b, wattn_b, qkv_b, S_LEN, 3 * EMB, EMB, EMB);
  attn_kernel<<<dim3(512), 256, 0, stream>>>(qkv_b, attn_b);
  // seed out with residual x, then attn proj as split-K x4 atomicAdd
  hipMemcpyAsync(out, x, (size_t)S_LEN * EMB * sizeof(float), hipMemcpyDeviceToDevice, stream);
  gemm_bt<4><<<dim3(16, 16, 4), 256, 0, stream>>>(attn_b, wproja_b, out, S_LEN, EMB, EMB, EMB / 4);
  ln_kernel<<<S_LEN, 256, 0, stream>>>(out, ln2w, h_b);
  // FC + GELU: [2048, 8192]
  gemm_bt<2><<<dim3(64, 16), 256, 0, stream>>>(h_b, wfc_b, f1_b, S_LEN, 4 * EMB, EMB, EMB);
  // FFN proj, split-K x4 atomicAdd into out
  gemm_bt<4><<<dim3(16, 16, 4), 256, 0, stream>>>(f1_b, wprojf_b, out, S_LEN, EMB, 4 * EMB, EMB);
}